// Round 11
// baseline (41.049 us; speedup 1.0000x reference)
//
#include <hip/hip_runtime.h>
#include <cstdint>

// DeepSeek-V3 MoE routing, MI355X. T=131072, E=256, G=8x32, topk_group=4, top_k=8.
// One wave per token; lane i owns experts 4i..4i+3.
// R11 = R10 (40.9us, VALU-issue-bound) + semantic VALU cuts:
//   - float-domain keys: k = bits(fmax(swb,0.5))-0x3F000000 (bit-identical to
//     R10's sortable-max-sub under the existing >=0.5 assumption; 3 ops vs 6)
//   - branchless LDS compaction (padded slab, cndmask slot, no exec churn)
//   - fused single store (lanes 0-7: idx, lanes 8-15: val)
//   - integer tie-compare in final ranking

constexpr int TOPK_GROUP  = 4;
constexpr int TOP_K       = 8;
constexpr float ROUTED_SCALING = 2.5f;
constexpr unsigned KEY_OFF = 0x3F000000u;   // bits(0.5f); low 16 bits zero

// DPP controls: quad_perm xor1/xor2, row_half_mirror (pairs within 8), row_mirror.
#define DPP_XOR1 0xB1
#define DPP_XOR2 0x4E
#define DPP_HM   0x141
#define DPP_M    0x140

template <int CTRL>
static __device__ __forceinline__ float dpp_f32(float x) {
  return __int_as_float(__builtin_amdgcn_mov_dpp(__float_as_int(x), CTRL, 0xF, 0xF, true));
}
template <int CTRL>
static __device__ __forceinline__ unsigned dpp_u32(unsigned x) {
  return (unsigned)__builtin_amdgcn_mov_dpp((int)x, CTRL, 0xF, 0xF, true);
}

static __device__ __forceinline__ int mbcnt64(unsigned long long m) {
  return __builtin_amdgcn_mbcnt_hi((unsigned)(m >> 32),
         __builtin_amdgcn_mbcnt_lo((unsigned)m, 0));
}

static __device__ __forceinline__ unsigned umax2(unsigned x, unsigned y) {
  return x > y ? x : y;
}

__global__ __launch_bounds__(256) void moe_route_kernel(
    const float* __restrict__ logits,   // [T, 256]
    const float* __restrict__ bias,     // [256]
    float* __restrict__ out_idx,        // [T, 8] indices as float
    float* __restrict__ out_val,        // [T, 8]
    int n_tokens) {
  const int lane = threadIdx.x & 63;
  const int wid  = threadIdx.x >> 6;
  const int token = blockIdx.x * 4 + wid;   // grid exact: no bounds guard
  __shared__ float2 buf[4][16];             // slots 0..7 real, 8..15 trash pad

  // ---- loads (32-bit indexing) ----
  const float4 lv = reinterpret_cast<const float4*>(logits)[token * 64 + lane];
  const float4 bv = reinterpret_cast<const float4*>(bias)[lane];

  // ---- direct-exp2 sigmoid: 1/(1 + 2^(-x*log2e)); raw v_rcp (<=1 ulp) ----
  const float sig0 = __builtin_amdgcn_rcpf(1.0f + __builtin_amdgcn_exp2f(lv.x * -1.44269504f));
  const float sig1 = __builtin_amdgcn_rcpf(1.0f + __builtin_amdgcn_exp2f(lv.y * -1.44269504f));
  const float sig2 = __builtin_amdgcn_rcpf(1.0f + __builtin_amdgcn_exp2f(lv.z * -1.44269504f));
  const float sig3 = __builtin_amdgcn_rcpf(1.0f + __builtin_amdgcn_exp2f(lv.w * -1.44269504f));
  const float swb0 = sig0 + bv.x;
  const float swb1 = sig1 + bv.y;
  const float swb2 = sig2 + bv.z;
  const float swb3 = sig3 + bv.w;

  // ---- group score: top-2 sum within each group (lanes 8g..8g+7), DPP merge ----
  const float h1 = fmaxf(swb0, swb1), l1 = fminf(swb0, swb1);
  const float h2 = fmaxf(swb2, swb3), l2 = fminf(swb2, swb3);
  float m1 = fmaxf(h1, h2);
  float m2 = fmaxf(fminf(h1, h2), fmaxf(l1, l2));
#define MERGE_LEV(CTRL)                                            \
  {                                                                \
    const float o1 = dpp_f32<CTRL>(m1);                            \
    const float o2 = dpp_f32<CTRL>(m2);                            \
    const float nm1 = fmaxf(m1, o1);                               \
    const float nm2 = fmaxf(fminf(m1, o1), fmaxf(m2, o2));         \
    m1 = nm1; m2 = nm2;                                            \
  }
  MERGE_LEV(DPP_XOR1)
  MERGE_LEV(DPP_XOR2)
  MERGE_LEV(DPP_HM)
#undef MERGE_LEV
  const float gscore = m1 + m2;

  // ---- group rank via one pairwise ballot ----
  const int g = lane >> 3;
  const int a = lane & 7;
  const float gs_o = __shfl(gscore, a << 3);
  const unsigned long long gm =
      __ballot((gs_o > gscore) || (gs_o == gscore && a < g));
  const int grank = __popc((unsigned)(gm >> (g << 3)) & 0xFFu);
  const bool gsel = grank < TOPK_GROUP;

  // ---- float-domain biased keys (< 2^25); non-selected groups -> 0.
  //      For swb>=0.5: bits(swb)-0x3F000000 == sortable(swb)-sortable(0.5),
  //      bit-identical to R10's key. Values <0.5 clamp to 0 (below thresh). ----
  const int ebase = lane << 2;
  const unsigned k0 = gsel ? ((unsigned)__float_as_int(fmaxf(swb0, 0.5f)) - KEY_OFF) : 0u;
  const unsigned k1 = gsel ? ((unsigned)__float_as_int(fmaxf(swb1, 0.5f)) - KEY_OFF) : 0u;
  const unsigned k2 = gsel ? ((unsigned)__float_as_int(fmaxf(swb2, 0.5f)) - KEY_OFF) : 0u;
  const unsigned k3 = gsel ? ((unsigned)__float_as_int(fmaxf(swb3, 0.5f)) - KEY_OFF) : 0u;

  // ---- radix select on bits [24:16]; early exit when count hits exactly 8 ----
  unsigned tf = 0u;
  for (int bit = 24; bit >= 16; --bit) {
    const unsigned cand = tf | (1u << bit);
    const int c = __popcll(__ballot(k0 >= cand)) + __popcll(__ballot(k1 >= cand))
                + __popcll(__ballot(k2 >= cand)) + __popcll(__ballot(k3 >= cand));
    if (c >= TOP_K) {
      tf = cand;
      if (c == TOP_K) break;   // exact: remaining bits can't change the set
    }
  }

  bool sel0 = k0 >= tf, sel1 = k1 >= tf, sel2 = k2 >= tf, sel3 = k3 >= tf;
  unsigned long long sm0 = __ballot(sel0), sm1 = __ballot(sel1),
                     sm2 = __ballot(sel2), sm3 = __ballot(sel3);
  const int cnt = __popcll(sm0) + __popcll(sm1) + __popcll(sm2) + __popcll(sm3);

  if (cnt > TOP_K) {   // wave-uniform slow path: ties within the 2^16 bucket
    const unsigned tg = tf + 0x10000u;   // KEY_OFF low16==0 -> bucket math unchanged
    const bool c0 = sel0 && (k0 < tg);
    const bool c1 = sel1 && (k1 < tg);
    const bool c2 = sel2 && (k2 < tg);
    const bool c3 = sel3 && (k3 < tg);
    const int nc = __popcll(__ballot(c0)) + __popcll(__ballot(c1))
                 + __popcll(__ballot(c2)) + __popcll(__ballot(c3));
    const int need2 = TOP_K - (cnt - nc);   // 1..8 to admit
    sel0 = sel0 && !c0; sel1 = sel1 && !c1;
    sel2 = sel2 && !c2; sel3 = sel3 && !c3;
    unsigned p0 = c0 ? (((k0 & 0xFFFFu) << 16) | (0xFFFFu - (unsigned)(ebase + 0))) : 0u;
    unsigned p1 = c1 ? (((k1 & 0xFFFFu) << 16) | (0xFFFFu - (unsigned)(ebase + 1))) : 0u;
    unsigned p2 = c2 ? (((k2 & 0xFFFFu) << 16) | (0xFFFFu - (unsigned)(ebase + 2))) : 0u;
    unsigned p3 = c3 ? (((k3 & 0xFFFFu) << 16) | (0xFFFFu - (unsigned)(ebase + 3))) : 0u;
    for (int r = 0; r < need2; ++r) {       // wave-uniform trips (exp. 1)
      unsigned mm = umax2(umax2(p0, p1), umax2(p2, p3));
      mm = umax2(mm, dpp_u32<DPP_XOR1>(mm));
      mm = umax2(mm, dpp_u32<DPP_XOR2>(mm));
      mm = umax2(mm, dpp_u32<DPP_HM>(mm));               // uniform within 8
      mm = umax2(mm, dpp_u32<DPP_M>(mm));                // uniform within 16
      mm = umax2(mm, (unsigned)__shfl_xor((int)mm, 16));
      mm = umax2(mm, (unsigned)__shfl_xor((int)mm, 32)); // wave-uniform
      const bool w0 = (p0 == mm), w1 = (p1 == mm), w2 = (p2 == mm), w3 = (p3 == mm);
      sel0 = sel0 || w0; sel1 = sel1 || w1;
      sel2 = sel2 || w2; sel3 = sel3 || w3;
      p0 = w0 ? 0u : p0; p1 = w1 ? 0u : p1;
      p2 = w2 ? 0u : p2; p3 = w3 ? 0u : p3;
    }
    sm0 = __ballot(sel0); sm1 = __ballot(sel1);
    sm2 = __ballot(sel2); sm3 = __ballot(sel3);
  }

  // ---- branchless compaction: selected -> slot 0..7, else trash slot 8+reg ----
  const int sbelow = mbcnt64(sm0) + mbcnt64(sm1) + mbcnt64(sm2) + mbcnt64(sm3);
  const int slot0 = sbelow;
  const int slot1 = slot0 + (int)sel0;
  const int slot2 = slot1 + (int)sel1;
  const int slot3 = slot2 + (int)sel2;

  float2* tb = buf[wid];
  tb[sel0 ? slot0 : 8]  = make_float2(__int_as_float(ebase + 0), sig0);
  tb[sel1 ? slot1 : 9]  = make_float2(__int_as_float(ebase + 1), sig1);
  tb[sel2 ? slot2 : 10] = make_float2(__int_as_float(ebase + 2), sig2);
  tb[sel3 ? slot3 : 11] = make_float2(__int_as_float(ebase + 3), sig3);
  asm volatile("s_waitcnt lgkmcnt(0)" ::: "memory");  // same-wave LDS RAW

  // ---- readback: own winner (l&7) AND partner winner (l>>3); 8-way broadcasts ----
  const int l8 = lane & 7;
  const float2 w  = tb[l8];
  const float2 wo = tb[lane >> 3];
  const float wsig = w.y;
  float ssum = wsig;
  ssum += dpp_f32<DPP_XOR1>(ssum);
  ssum += dpp_f32<DPP_XOR2>(ssum);
  ssum += dpp_f32<DPP_HM>(ssum);
  const float inv = __builtin_amdgcn_rcpf(ssum);   // <=1 ulp; ssum >= ~1e-3
  const float val = wsig * inv * ROUTED_SCALING;   // identical op order both uses
  const float v_o = wo.y * inv * ROUTED_SCALING;   // bit-identical to owner's val
  const int widx_i = __float_as_int(w.x);
  const int i_o_i  = __float_as_int(wo.x);

  // ---- final order via one pairwise ballot: winner a=(l&7) vs b=(l>>3);
  //      tie-break on integer expert idx (same order as float for idx>=0) ----
  const unsigned long long rm =
      __ballot((val > v_o) || (val == v_o && widx_i < i_o_i));
  const int rank = __popc((unsigned)(rm >> (l8 << 3)) & 0xFFu);

  // ---- fused store: lanes 0-7 write idx (as float), lanes 8-15 write val ----
  if (lane < 16) {
    float* base = (lane < 8) ? out_idx : out_val;
    base[token * TOP_K + rank] = (lane < 8) ? (float)widx_i : val;
  }
}

extern "C" void kernel_launch(void* const* d_in, const int* in_sizes, int n_in,
                              void* d_out, int out_size, void* d_ws, size_t ws_size,
                              hipStream_t stream) {
  const float* logits = (const float*)d_in[0];
  const float* bias   = (const float*)d_in[1];
  float* out = (float*)d_out;

  const int n_tokens = in_sizes[0] / 256;
  float* out_idx = out;
  float* out_val = out + (size_t)n_tokens * TOP_K;

  const int blocks = (n_tokens + 3) / 4;   // 4 waves (tokens) per 256-thread block
  moe_route_kernel<<<blocks, 256, 0, stream>>>(logits, bias, out_idx, out_val, n_tokens);
}